// Round 5
// baseline (1001.948 us; speedup 1.0000x reference)
//
#include <hip/hip_runtime.h>

#define T_DIM 1024
#define B_DIM 512
#define OBS_DIM 64
#define H_DIM 128
#define G3 384
#define A_DIM 16
#define CT 256
#define NCHUNK 4

typedef __bf16 bf16;
typedef __attribute__((ext_vector_type(4))) __bf16 bf16x4;
typedef __attribute__((ext_vector_type(8))) __bf16 bf16x8;
typedef __attribute__((ext_vector_type(4))) float f32x4;

#define MFMA(a, b, c) __builtin_amdgcn_mfma_f32_16x16x32_bf16((a), (b), (c), 0, 0, 0)

__device__ __forceinline__ float sigm(float x) { return 1.0f / (1.0f + __expf(-x)); }
__device__ __forceinline__ float tanh_f(float x) { return 1.0f - 2.0f / (__expf(2.0f * x) + 1.0f); }

// ---------------- prep: bf16 transposed weights + h_state init ----------------
__global__ __launch_bounds__(256) void prep_k(
    const float* __restrict__ hidden, const int* __restrict__ dones,
    const float* __restrict__ W_emb, const float* __restrict__ Wi,
    const float* __restrict__ Wh, const float* __restrict__ Wa1,
    const float* __restrict__ Wa2, const float* __restrict__ Wc1,
    const float* __restrict__ Wc2,
    bf16* __restrict__ wembT, bf16* __restrict__ wiT, bf16* __restrict__ whT,
    bf16* __restrict__ wa1T, bf16* __restrict__ wa2T, bf16* __restrict__ wc1T,
    bf16* __restrict__ wc2T, float* __restrict__ h_state) {
  int i = blockIdx.x * 256 + threadIdx.x;
  if (i < 8192) { int n = i / OBS_DIM, k = i % OBS_DIM; wembT[i] = (bf16)W_emb[k * H_DIM + n]; return; }
  i -= 8192;
  if (i < 49152) { int g = i / H_DIM, k = i % H_DIM; wiT[i] = (bf16)Wi[k * G3 + g]; return; }
  i -= 49152;
  if (i < 49152) { int g = i / H_DIM, k = i % H_DIM; whT[i] = (bf16)Wh[k * G3 + g]; return; }
  i -= 49152;
  if (i < 16384) { int n = i / H_DIM, k = i % H_DIM; wa1T[i] = (bf16)Wa1[k * H_DIM + n]; return; }
  i -= 16384;
  if (i < 2048) { int a = i / H_DIM, k = i % H_DIM; wa2T[i] = (bf16)Wa2[k * A_DIM + a]; return; }
  i -= 2048;
  if (i < 16384) { int n = i / H_DIM, k = i % H_DIM; wc1T[i] = (bf16)Wc1[k * H_DIM + n]; return; }
  i -= 16384;
  if (i < 2048) { int r = i / H_DIM, k = i % H_DIM; wc2T[i] = (r == 0) ? (bf16)Wc2[k] : (bf16)0.0f; return; }
  i -= 2048;
  if (i < 65536) { int b = i / H_DIM; h_state[i] = dones[b] ? 0.0f : hidden[i]; return; }
}

// ================= role bodies (share one 50176-B LDS block) =================

// ---- phase1 body: weight-stationary, 512 rows (32 row-tiles) per block ------
__device__ __forceinline__ void phase1_body(
    char* smem, int bid, const float* __restrict__ obs,
    const float* __restrict__ b_emb, const float* __restrict__ bi,
    const bf16* __restrict__ wembT, const bf16* __restrict__ wiT,
    bf16* __restrict__ xi, int row_base) {
  bf16 (*obs_lds)[72]  = (bf16(*)[72])smem;            // 2304 B
  bf16 (*emb_lds)[136] = (bf16(*)[136])(smem + 2304);  // 4352 B
  bf16 (*strip)[392]   = (bf16(*)[392])(smem + 6656);  // 12544 B
  int tid = threadIdx.x, wave = tid >> 6, lane = tid & 63;
  int nl = lane & 15, q = lane >> 4;

  bf16x8 we[2][2], wi_f[6][4];
  float bev[2], biv[6];
#pragma unroll
  for (int e = 0; e < 2; ++e) {
    int nt = wave * 2 + e;
#pragma unroll
    for (int kb = 0; kb < 2; ++kb)
      we[e][kb] = *(const bf16x8*)(wembT + (nt * 16 + nl) * OBS_DIM + kb * 32 + q * 8);
    bev[e] = b_emb[nt * 16 + nl];
  }
#pragma unroll
  for (int j = 0; j < 6; ++j) {
    int nt = wave * 6 + j;
#pragma unroll
    for (int kb = 0; kb < 4; ++kb)
      wi_f[j][kb] = *(const bf16x8*)(wiT + (nt * 16 + nl) * H_DIM + kb * 32 + q * 8);
    biv[j] = bi[nt * 16 + nl];
  }

  int srow = tid >> 4, scol = (tid & 15) * 4;
  for (int rt = 0; rt < 32; ++rt) {
    int r0 = bid * 512 + rt * 16;  // chunk-local row base
    {   // stage obs tile (f32 -> bf16), 256 thr x 1 float4
      const float* src = obs + ((long)row_base + r0 + srow) * OBS_DIM + scol;
      float4 vv = *(const float4*)src;
      bf16x4 b; b[0] = (bf16)vv.x; b[1] = (bf16)vv.y; b[2] = (bf16)vv.z; b[3] = (bf16)vv.w;
      *(bf16x4*)&obs_lds[srow][scol] = b;
    }
    __syncthreads();
    bf16x8 ao[2];
#pragma unroll
    for (int kb = 0; kb < 2; ++kb) ao[kb] = *(const bf16x8*)&obs_lds[nl][kb * 32 + q * 8];
#pragma unroll
    for (int e = 0; e < 2; ++e) {
      f32x4 c = {0.f, 0.f, 0.f, 0.f};
      c = MFMA(ao[0], we[e][0], c);
      c = MFMA(ao[1], we[e][1], c);
#pragma unroll
      for (int r = 0; r < 4; ++r) {
        float v = c[r] + bev[e];
        emb_lds[q * 4 + r][(wave * 2 + e) * 16 + nl] = (bf16)(v > 0.f ? v : 0.f);
      }
    }
    __syncthreads();
    bf16x8 ae[4];
#pragma unroll
    for (int kb = 0; kb < 4; ++kb) ae[kb] = *(const bf16x8*)&emb_lds[nl][kb * 32 + q * 8];
#pragma unroll
    for (int j = 0; j < 6; ++j) {
      int nt = wave * 6 + j;
      f32x4 c = {0.f, 0.f, 0.f, 0.f};
#pragma unroll
      for (int kb = 0; kb < 4; ++kb) c = MFMA(ae[kb], wi_f[j][kb], c);
      int gate = nt >> 3, dloc = (nt & 7) * 16 + nl;
      int pos = (gate < 2) ? (2 * dloc + gate) : (256 + dloc);
#pragma unroll
      for (int r = 0; r < 4; ++r) strip[q * 4 + r][pos] = (bf16)(c[r] + biv[j]);
    }
    __syncthreads();
    bf16* dst = xi + (long)r0 * G3;
#pragma unroll
    for (int it = 0; it < 3; ++it) {
      int e0 = (it * 256 + tid) * 8;
      int row = e0 / G3, col = e0 % G3;
      *(int4*)(dst + e0) = *(const int4*)&strip[row][col];
    }
  }
}

// ---- scan body: GRU over CT steps, 2 chains per block (1 block/CU) ----------
// Gate-ordered tile computation (r,r,z,z,n,n), each tile split into two
// independent 2-deep MFMA chains + f32x4 add, so r/z sigmoids issue on the
// VALU pipe while later tiles still occupy the matrix pipe.
__device__ __forceinline__ void scan_body(
    char* smem, int bid, const bf16* __restrict__ xi,
    const int* __restrict__ dones, const float* __restrict__ bh_n,
    const bf16* __restrict__ whT, float* __restrict__ h_state,
    bf16* __restrict__ y, float* __restrict__ hidden_out, int chunk) {
  bf16 (*hb)[16][136]      = (bf16(*)[16][136])smem;              // 8704 B
  bf16 (*xibuf)[8][2][400] = (bf16(*)[8][2][400])(smem + 8704);   // 25600 B
  int  (*dn)[2]            = (int(*)[2])(smem + 34304);           // 2056 B

  __builtin_amdgcn_s_setprio(1);   // win SIMD arbitration vs worker waves

  int tid = threadIdx.x;
  int wave = tid >> 6, lane = tid & 63;
  int nl = lane & 15, q = lane >> 4;
  int b0 = bid * 2;
  int ch = q & 1;
  int hsel = q >> 1;
  int dim = wave * 16 + (hsel << 6) + nl;

  for (int i = tid; i < 2 * 16 * 136; i += 256) ((bf16*)hb)[i] = (bf16)0.0f;
  for (int i = tid; i <= CT; i += 256) {
    int t = chunk * CT + i;
    dn[i][0] = (t < T_DIM) ? dones[t * B_DIM + b0] : 0;
    dn[i][1] = (t < T_DIM) ? dones[t * B_DIM + b0 + 1] : 0;
  }
  int c0 = tid, c1 = 256 + tid, c2 = 512 + tid;
  int t0 = c0 / 96, p0 = c0 % 96, sc0 = p0 / 48, o0 = (p0 % 48) * 8;
  int t1 = c1 / 96, p1 = c1 % 96, sc1 = p1 / 48, o1 = (p1 % 48) * 8;
  int t2 = c2 / 96, p2 = c2 % 96, sc2 = p2 / 48, o2 = (p2 % 48) * 8;
  const long PSTR = (long)8 * B_DIM * G3;
  const bf16* pfs0 = xi + ((long)(8 + t0) * B_DIM + b0 + sc0) * G3 + o0;
  const bf16* pfs1 = xi + ((long)(8 + t1) * B_DIM + b0 + sc1) * G3 + o1;
  const bf16* pfs2 = xi + ((long)(8 + t2) * B_DIM + b0 + sc2) * G3 + o2;
  *(int4*)&xibuf[0][t0][sc0][o0] = *(const int4*)(xi + ((long)t0 * B_DIM + b0 + sc0) * G3 + o0);
  *(int4*)&xibuf[0][t1][sc1][o1] = *(const int4*)(xi + ((long)t1 * B_DIM + b0 + sc1) * G3 + o1);
  *(int4*)&xibuf[0][t2][sc2][o2] = *(const int4*)(xi + ((long)t2 * B_DIM + b0 + sc2) * G3 + o2);
  __syncthreads();

  float hprev = h_state[(b0 + ch) * H_DIM + dim];
  {
    bf16 h0 = (bf16)hprev;
    hb[0][0 + ch][dim] = h0;  hb[0][4 + ch][dim] = h0;
    hb[0][8 + ch][dim] = h0;  hb[0][12 + ch][dim] = h0;
  }
  bf16x8 wf[6][4];
#pragma unroll
  for (int g = 0; g < 3; ++g)
#pragma unroll
    for (int hI = 0; hI < 2; ++hI)
#pragma unroll
      for (int kb = 0; kb < 4; ++kb)
        wf[g * 2 + hI][kb] =
            *(const bf16x8*)(whT + ((g * 8 + wave + 4 * hI) * 16 + nl) * H_DIM + kb * 32 + q * 8);
  float bhn = bh_n[dim];
  bf16* yp = y + (long)(b0 + ch) * H_DIM + dim;
  __syncthreads();

  int4 pfr0, pfr1, pfr2;

#define BAR()                                                                  \
  do {                                                                         \
    asm volatile("s_waitcnt lgkmcnt(0)" ::: "memory");                         \
    __builtin_amdgcn_sched_barrier(0);                                         \
    __builtin_amdgcn_s_barrier();                                              \
    __builtin_amdgcn_sched_barrier(0);                                         \
  } while (0)

#define TILE2(J, CA)                                                           \
  do {                                                                         \
    f32x4 a_ = {0.f, 0.f, 0.f, 0.f}, b_ = {0.f, 0.f, 0.f, 0.f};                \
    a_ = MFMA(ha0, wf[J][0], a_);  b_ = MFMA(ha2, wf[J][2], b_);               \
    a_ = MFMA(ha1, wf[J][1], a_);  b_ = MFMA(ha3, wf[J][3], b_);               \
    CA = a_ + b_;                                                              \
  } while (0)

#define GSTEP(CUR, TS, TB, PF)                                                 \
  do {                                                                         \
    const int p_ = (TS) & 1;                                                   \
    bf16x8 ha0 = *(const bf16x8*)&hb[p_][nl][0 * 32 + q * 8];                  \
    bf16x8 ha1 = *(const bf16x8*)&hb[p_][nl][1 * 32 + q * 8];                  \
    bf16x8 ha2 = *(const bf16x8*)&hb[p_][nl][2 * 32 + q * 8];                  \
    bf16x8 ha3 = *(const bf16x8*)&hb[p_][nl][3 * 32 + q * 8];                  \
    const bf16* xrow_ = &xibuf[CUR][TS][ch][0];                                \
    unsigned urz_ = *(const unsigned*)(xrow_ + 2 * dim);                       \
    float xnv_ = (float)xrow_[256 + dim];                                      \
    int dnv_ = dn[(TB) + (TS) + 1][ch];                                        \
    if ((TS) == 0 && (PF)) {                                                   \
      pfr0 = *(const int4*)pfs0; pfs0 += PSTR;                                 \
      pfr1 = *(const int4*)pfs1; pfs1 += PSTR;                                 \
      pfr2 = *(const int4*)pfs2; pfs2 += PSTR;                                 \
    }                                                                          \
    union { unsigned u; float f; } cvr_, cvz_;                                 \
    cvr_.u = urz_ << 16; cvz_.u = urz_ & 0xffff0000u;                          \
    f32x4 c0_, c1_, c2_, c3_, c4_, c5_;                                        \
    TILE2(0, c0_); TILE2(1, c1_);                                              \
    float hr_ = hsel ? (ch ? c1_[1] : c1_[0]) : (ch ? c0_[1] : c0_[0]);        \
    float r_ = sigm(cvr_.f + hr_);                                             \
    TILE2(2, c2_); TILE2(3, c3_);                                              \
    float hz_ = hsel ? (ch ? c3_[1] : c3_[0]) : (ch ? c2_[1] : c2_[0]);        \
    float z_ = sigm(cvz_.f + hz_);                                             \
    if ((TS) == 7 && (PF)) {                                                   \
      *(int4*)&xibuf[(CUR) ^ 1][t0][sc0][o0] = pfr0;                           \
      *(int4*)&xibuf[(CUR) ^ 1][t1][sc1][o1] = pfr1;                           \
      *(int4*)&xibuf[(CUR) ^ 1][t2][sc2][o2] = pfr2;                           \
    }                                                                          \
    TILE2(4, c4_); TILE2(5, c5_);                                              \
    float hn_ = hsel ? (ch ? c5_[1] : c5_[0]) : (ch ? c4_[1] : c4_[0]);        \
    float n_ = tanh_f(xnv_ + r_ * (hn_ + bhn));                                \
    float hnew_ = (1.0f - z_) * n_ + z_ * hprev;                               \
    float heff_ = dnv_ ? 0.0f : hnew_;                                         \
    *yp = (bf16)hnew_; yp += B_DIM * H_DIM;                                    \
    bf16 hbv_ = (bf16)heff_;                                                   \
    hb[p_ ^ 1][0 + ch][dim] = hbv_;  hb[p_ ^ 1][4 + ch][dim] = hbv_;           \
    hb[p_ ^ 1][8 + ch][dim] = hbv_;  hb[p_ ^ 1][12 + ch][dim] = hbv_;          \
    hprev = heff_;                                                             \
    BAR();                                                                     \
  } while (0)

  for (int tb = 0; tb < CT; tb += 16) {
    GSTEP(0, 0, tb, 1); GSTEP(0, 1, tb, 1); GSTEP(0, 2, tb, 1); GSTEP(0, 3, tb, 1);
    GSTEP(0, 4, tb, 1); GSTEP(0, 5, tb, 1); GSTEP(0, 6, tb, 1); GSTEP(0, 7, tb, 1);
    const int pfB = (tb + 16 < CT) ? 1 : 0;
    GSTEP(1, 0, tb + 8, pfB); GSTEP(1, 1, tb + 8, pfB); GSTEP(1, 2, tb + 8, pfB);
    GSTEP(1, 3, tb + 8, pfB); GSTEP(1, 4, tb + 8, pfB); GSTEP(1, 5, tb + 8, pfB);
    GSTEP(1, 6, tb + 8, pfB); GSTEP(1, 7, tb + 8, pfB);
  }
#undef GSTEP
#undef TILE2
#undef BAR
  __builtin_amdgcn_s_setprio(0);

  // heff(last) == hnew(last) on the final chunk: dn[CT] there is 0 (t >= T_DIM)
  h_state[(b0 + ch) * H_DIM + dim] = hprev;
  if (chunk == NCHUNK - 1) hidden_out[(b0 + ch) * H_DIM + dim] = hprev;
}

// ---- heads body: weight-stationary, 512 rows (32 row-tiles) per block -------
__device__ __forceinline__ void heads_body(
    char* smem, int bid, const bf16* __restrict__ y,
    const float* __restrict__ ba1, const float* __restrict__ ba2,
    const float* __restrict__ bc1, const float* __restrict__ bc2,
    const bf16* __restrict__ wa1T, const bf16* __restrict__ wa2T,
    const bf16* __restrict__ wc1T, const bf16* __restrict__ wc2T,
    float* __restrict__ logits, float* __restrict__ v, int t_base) {
  bf16  (*y_lds)[136] = (bf16(*)[136])smem;              // 4352 B
  bf16  (*a1s)[136]   = (bf16(*)[136])(smem + 4352);     // 4352 B
  bf16  (*c1s)[136]   = (bf16(*)[136])(smem + 8704);     // 4352 B
  float (*s_o)[16]    = (float(*)[16])(smem + 13056);    // 1024 B
  float (*s_v)        = (float*)(smem + 14080);          // 64 B
  int tid = threadIdx.x, wave = tid >> 6, lane = tid & 63;
  int nl = lane & 15, q = lane >> 4;

  bf16x8 wa1f[2][4], wc1f[2][4], wa2f[4], wc2f[4];
  float ba1v[2], bc1v[2];
#pragma unroll
  for (int e = 0; e < 2; ++e) {
    int nt = wave * 2 + e;
#pragma unroll
    for (int kb = 0; kb < 4; ++kb) {
      wa1f[e][kb] = *(const bf16x8*)(wa1T + (nt * 16 + nl) * H_DIM + kb * 32 + q * 8);
      wc1f[e][kb] = *(const bf16x8*)(wc1T + (nt * 16 + nl) * H_DIM + kb * 32 + q * 8);
    }
    ba1v[e] = ba1[nt * 16 + nl];
    bc1v[e] = bc1[nt * 16 + nl];
  }
#pragma unroll
  for (int kb = 0; kb < 4; ++kb) {
    wa2f[kb] = *(const bf16x8*)(wa2T + nl * H_DIM + kb * 32 + q * 8);
    wc2f[kb] = *(const bf16x8*)(wc2T + nl * H_DIM + kb * 32 + q * 8);
  }
  float ba2v = ba2[nl], bc2v = bc2[0];

  int srow = tid >> 4, scol = (tid & 15) * 8;
  for (int rt = 0; rt < 32; ++rt) {
    int r0 = bid * 512 + rt * 16;          // chunk-local row base
    long gr0 = (long)t_base * B_DIM + r0;  // global row base
    *(int4*)&y_lds[srow][scol] = *(const int4*)(y + (long)(r0 + srow) * H_DIM + scol);
    __syncthreads();
    bf16x8 ya[4];
#pragma unroll
    for (int kb = 0; kb < 4; ++kb) ya[kb] = *(const bf16x8*)&y_lds[nl][kb * 32 + q * 8];
#pragma unroll
    for (int e = 0; e < 2; ++e) {
      f32x4 ca = {0.f, 0.f, 0.f, 0.f}, cc = {0.f, 0.f, 0.f, 0.f};
#pragma unroll
      for (int kb = 0; kb < 4; ++kb) {
        ca = MFMA(ya[kb], wa1f[e][kb], ca);
        cc = MFMA(ya[kb], wc1f[e][kb], cc);
      }
      int colb = (wave * 2 + e) * 16 + nl;
#pragma unroll
      for (int r = 0; r < 4; ++r) {
        float va = ca[r] + ba1v[e];
        float vc = cc[r] + bc1v[e];
        a1s[q * 4 + r][colb] = (bf16)(va > 0.f ? va : 0.f);
        c1s[q * 4 + r][colb] = (bf16)(vc > 0.f ? vc : 0.f);
      }
    }
    __syncthreads();
    if (wave == 0) {
      bf16x8 a1f[4];
#pragma unroll
      for (int kb = 0; kb < 4; ++kb) a1f[kb] = *(const bf16x8*)&a1s[nl][kb * 32 + q * 8];
      f32x4 c = {0.f, 0.f, 0.f, 0.f};
#pragma unroll
      for (int kb = 0; kb < 4; ++kb) c = MFMA(a1f[kb], wa2f[kb], c);
#pragma unroll
      for (int r = 0; r < 4; ++r) s_o[q * 4 + r][nl] = c[r] + ba2v;
    } else if (wave == 1) {
      bf16x8 c1f[4];
#pragma unroll
      for (int kb = 0; kb < 4; ++kb) c1f[kb] = *(const bf16x8*)&c1s[nl][kb * 32 + q * 8];
      f32x4 c = {0.f, 0.f, 0.f, 0.f};
#pragma unroll
      for (int kb = 0; kb < 4; ++kb) c = MFMA(c1f[kb], wc2f[kb], c);
      if (nl == 0) {
#pragma unroll
        for (int r = 0; r < 4; ++r) s_v[q * 4 + r] = c[r] + bc2v;
      }
    }
    __syncthreads();
    if (tid < 64) {
      *(int4*)(logits + gr0 * A_DIM + tid * 4) = *(const int4*)&s_o[tid >> 2][(tid & 3) * 4];
    } else if (tid < 80) {
      v[gr0 + (tid - 64)] = s_v[tid - 64];
    }
  }
}

// ---- fused pipeline kernel: scan(cs) ∥ phase1(cs+1) ∥ heads(cs-1) ------------
// 768 blocks = 3 blocks/CU (LDS-limited): 1 scan + 1 phase1 + 1 heads per CU.
__global__ __launch_bounds__(256, 3) void fused_k(
    const float* __restrict__ obs, const float* __restrict__ b_emb,
    const float* __restrict__ bi, const bf16* __restrict__ wembT,
    const bf16* __restrict__ wiT, bf16* __restrict__ xi0, bf16* __restrict__ xi1,
    const int* __restrict__ dones, const float* __restrict__ bh_n,
    const bf16* __restrict__ whT, float* __restrict__ h_state,
    bf16* __restrict__ y0, bf16* __restrict__ y1, float* __restrict__ hidden_out,
    const float* __restrict__ ba1, const float* __restrict__ ba2,
    const float* __restrict__ bc1, const float* __restrict__ bc2,
    const bf16* __restrict__ wa1T, const bf16* __restrict__ wa2T,
    const bf16* __restrict__ wc1T, const bf16* __restrict__ wc2T,
    float* __restrict__ logits, float* __restrict__ v, int cs) {
  __shared__ __align__(16) char smem[50176];
  int bid = blockIdx.x;
  if (bid < 256) {
    if (cs >= 0 && cs < NCHUNK)
      scan_body(smem, bid, (cs & 1) ? xi1 : xi0, dones, bh_n, whT, h_state,
                (cs & 1) ? y1 : y0, hidden_out, cs);
    return;
  }
  if (bid < 512) {
    int cp = cs + 1;
    if (cp >= 0 && cp < NCHUNK)
      phase1_body(smem, bid - 256, obs, b_emb, bi, wembT, wiT,
                  (cp & 1) ? xi1 : xi0, cp * CT * B_DIM);
    return;
  }
  {
    int ch2 = cs - 1;
    if (ch2 >= 0 && ch2 < NCHUNK)
      heads_body(smem, bid - 512, (ch2 & 1) ? y1 : y0, ba1, ba2, bc1, bc2,
                 wa1T, wa2T, wc1T, wc2T, logits, v, ch2 * CT);
  }
}

// ---------------- launch ------------------------------------------------------
extern "C" void kernel_launch(void* const* d_in, const int* in_sizes, int n_in,
                              void* d_out, int out_size, void* d_ws, size_t ws_size,
                              hipStream_t stream) {
  const float* hidden = (const float*)d_in[0];
  const float* obs    = (const float*)d_in[1];
  const int*   dones  = (const int*)d_in[2];
  const float* W_emb  = (const float*)d_in[3];
  const float* b_emb  = (const float*)d_in[4];
  const float* Wi     = (const float*)d_in[5];
  const float* bi     = (const float*)d_in[6];
  const float* Wh     = (const float*)d_in[7];
  const float* bh_n   = (const float*)d_in[8];
  const float* Wa1    = (const float*)d_in[9];
  const float* ba1    = (const float*)d_in[10];
  const float* Wa2    = (const float*)d_in[11];
  const float* ba2    = (const float*)d_in[12];
  const float* Wc1    = (const float*)d_in[13];
  const float* bc1    = (const float*)d_in[14];
  const float* Wc2    = (const float*)d_in[15];
  const float* bc2    = (const float*)d_in[16];

  float* out_hidden = (float*)d_out;
  float* out_logits = out_hidden + B_DIM * H_DIM;
  float* out_v      = out_logits + (long)T_DIM * B_DIM * A_DIM;

  char* ws = (char*)d_ws;
  bf16*  wembT   = (bf16*)(ws + 0);
  bf16*  wiT     = (bf16*)(ws + 16384);
  bf16*  whT     = (bf16*)(ws + 114688);
  bf16*  wa1T    = (bf16*)(ws + 212992);
  bf16*  wa2T    = (bf16*)(ws + 245760);
  bf16*  wc1T    = (bf16*)(ws + 249856);
  bf16*  wc2T    = (bf16*)(ws + 282624);
  float* h_state = (float*)(ws + 286720);
  bf16*  xi0     = (bf16*)(ws + 548864);       // 100.66 MB per chunk buffer
  bf16*  xi1     = (bf16*)(ws + 101212160);
  bf16*  y0      = (bf16*)(ws + 201875456);    // 33.55 MB per chunk buffer
  bf16*  y1      = (bf16*)(ws + 235429888);    // end 268.98 MB

  prep_k<<<816, 256, 0, stream>>>(hidden, dones, W_emb, Wi, Wh, Wa1, Wa2, Wc1, Wc2,
                                  wembT, wiT, whT, wa1T, wa2T, wc1T, wc2T, h_state);
  for (int cs = -1; cs <= NCHUNK; ++cs) {
    fused_k<<<768, 256, 0, stream>>>(obs, b_emb, bi, wembT, wiT, xi0, xi1,
                                     dones, bh_n, whT, h_state, y0, y1, out_hidden,
                                     ba1, ba2, bc1, bc2, wa1T, wa2T, wc1T, wc2T,
                                     out_logits, out_v, cs);
  }
  (void)in_sizes; (void)n_in; (void)out_size; (void)ws_size;
}

// Round 7
// 910.648 us; speedup vs baseline: 1.1003x; 1.1003x over previous
//
#include <hip/hip_runtime.h>

#define T_DIM 1024
#define B_DIM 512
#define OBS_DIM 64
#define H_DIM 128
#define G3 384
#define A_DIM 16
#define CT 256
#define NCHUNK 4

typedef __bf16 bf16;
typedef __attribute__((ext_vector_type(4))) __bf16 bf16x4;
typedef __attribute__((ext_vector_type(8))) __bf16 bf16x8;
typedef __attribute__((ext_vector_type(4))) float f32x4;

#define MFMA(a, b, c) __builtin_amdgcn_mfma_f32_16x16x32_bf16((a), (b), (c), 0, 0, 0)

__device__ __forceinline__ float sigm(float x) { return 1.0f / (1.0f + __expf(-x)); }
__device__ __forceinline__ float tanh_f(float x) { return 1.0f - 2.0f / (__expf(2.0f * x) + 1.0f); }

// ---------------- prep: bf16 transposed weights + h_state init ----------------
__global__ __launch_bounds__(256) void prep_k(
    const float* __restrict__ hidden, const int* __restrict__ dones,
    const float* __restrict__ W_emb, const float* __restrict__ Wi,
    const float* __restrict__ Wh, const float* __restrict__ Wa1,
    const float* __restrict__ Wa2, const float* __restrict__ Wc1,
    const float* __restrict__ Wc2,
    bf16* __restrict__ wembT, bf16* __restrict__ wiT, bf16* __restrict__ whT,
    bf16* __restrict__ wa1T, bf16* __restrict__ wa2T, bf16* __restrict__ wc1T,
    bf16* __restrict__ wc2T, float* __restrict__ h_state) {
  int i = blockIdx.x * 256 + threadIdx.x;
  if (i < 8192) { int n = i / OBS_DIM, k = i % OBS_DIM; wembT[i] = (bf16)W_emb[k * H_DIM + n]; return; }
  i -= 8192;
  if (i < 49152) { int g = i / H_DIM, k = i % H_DIM; wiT[i] = (bf16)Wi[k * G3 + g]; return; }
  i -= 49152;
  if (i < 49152) { int g = i / H_DIM, k = i % H_DIM; whT[i] = (bf16)Wh[k * G3 + g]; return; }
  i -= 49152;
  if (i < 16384) { int n = i / H_DIM, k = i % H_DIM; wa1T[i] = (bf16)Wa1[k * H_DIM + n]; return; }
  i -= 16384;
  if (i < 2048) { int a = i / H_DIM, k = i % H_DIM; wa2T[i] = (bf16)Wa2[k * A_DIM + a]; return; }
  i -= 2048;
  if (i < 16384) { int n = i / H_DIM, k = i % H_DIM; wc1T[i] = (bf16)Wc1[k * H_DIM + n]; return; }
  i -= 16384;
  if (i < 2048) { int r = i / H_DIM, k = i % H_DIM; wc2T[i] = (r == 0) ? (bf16)Wc2[k] : (bf16)0.0f; return; }
  i -= 2048;
  if (i < 65536) { int b = i / H_DIM; h_state[i] = dones[b] ? 0.0f : hidden[i]; return; }
}

// ================= role bodies (share one 50176-B LDS block) =================

// ---- phase1 body: weight-stationary, 512 rows (32 row-tiles) per block ------
__device__ __forceinline__ void phase1_body(
    char* smem, int bid, const float* __restrict__ obs,
    const float* __restrict__ b_emb, const float* __restrict__ bi,
    const bf16* __restrict__ wembT, const bf16* __restrict__ wiT,
    bf16* __restrict__ xi, int row_base) {
  bf16 (*obs_lds)[72]  = (bf16(*)[72])smem;            // 2304 B
  bf16 (*emb_lds)[136] = (bf16(*)[136])(smem + 2304);  // 4352 B
  bf16 (*strip)[392]   = (bf16(*)[392])(smem + 6656);  // 12544 B
  int tid = threadIdx.x, wave = tid >> 6, lane = tid & 63;
  int nl = lane & 15, q = lane >> 4;

  bf16x8 we[2][2], wi_f[6][4];
  float bev[2], biv[6];
#pragma unroll
  for (int e = 0; e < 2; ++e) {
    int nt = wave * 2 + e;
#pragma unroll
    for (int kb = 0; kb < 2; ++kb)
      we[e][kb] = *(const bf16x8*)(wembT + (nt * 16 + nl) * OBS_DIM + kb * 32 + q * 8);
    bev[e] = b_emb[nt * 16 + nl];
  }
#pragma unroll
  for (int j = 0; j < 6; ++j) {
    int nt = wave * 6 + j;
#pragma unroll
    for (int kb = 0; kb < 4; ++kb)
      wi_f[j][kb] = *(const bf16x8*)(wiT + (nt * 16 + nl) * H_DIM + kb * 32 + q * 8);
    biv[j] = bi[nt * 16 + nl];
  }

  int srow = tid >> 4, scol = (tid & 15) * 4;
  for (int rt = 0; rt < 32; ++rt) {
    int r0 = bid * 512 + rt * 16;  // chunk-local row base
    {   // stage obs tile (f32 -> bf16), 256 thr x 1 float4
      const float* src = obs + ((long)row_base + r0 + srow) * OBS_DIM + scol;
      float4 vv = *(const float4*)src;
      bf16x4 b; b[0] = (bf16)vv.x; b[1] = (bf16)vv.y; b[2] = (bf16)vv.z; b[3] = (bf16)vv.w;
      *(bf16x4*)&obs_lds[srow][scol] = b;
    }
    __syncthreads();
    bf16x8 ao[2];
#pragma unroll
    for (int kb = 0; kb < 2; ++kb) ao[kb] = *(const bf16x8*)&obs_lds[nl][kb * 32 + q * 8];
#pragma unroll
    for (int e = 0; e < 2; ++e) {
      f32x4 c = {0.f, 0.f, 0.f, 0.f};
      c = MFMA(ao[0], we[e][0], c);
      c = MFMA(ao[1], we[e][1], c);
#pragma unroll
      for (int r = 0; r < 4; ++r) {
        float v = c[r] + bev[e];
        emb_lds[q * 4 + r][(wave * 2 + e) * 16 + nl] = (bf16)(v > 0.f ? v : 0.f);
      }
    }
    __syncthreads();
    bf16x8 ae[4];
#pragma unroll
    for (int kb = 0; kb < 4; ++kb) ae[kb] = *(const bf16x8*)&emb_lds[nl][kb * 32 + q * 8];
#pragma unroll
    for (int j = 0; j < 6; ++j) {
      int nt = wave * 6 + j;
      f32x4 c = {0.f, 0.f, 0.f, 0.f};
#pragma unroll
      for (int kb = 0; kb < 4; ++kb) c = MFMA(ae[kb], wi_f[j][kb], c);
      int gate = nt >> 3, dloc = (nt & 7) * 16 + nl;
      int pos = (gate < 2) ? (2 * dloc + gate) : (256 + dloc);
#pragma unroll
      for (int r = 0; r < 4; ++r) strip[q * 4 + r][pos] = (bf16)(c[r] + biv[j]);
    }
    __syncthreads();
    bf16* dst = xi + (long)r0 * G3;
#pragma unroll
    for (int it = 0; it < 3; ++it) {
      int e0 = (it * 256 + tid) * 8;
      int row = e0 / G3, col = e0 % G3;
      *(int4*)(dst + e0) = *(const int4*)&strip[row][col];
    }
  }
}

// ---- scan body: GRU over CT steps, 2 chains per block (1 block/CU) ----------
// hb is now [2 dbuf][2 chains][136]: A-fragment row nl only ever needs
// h[nl&1] (D rows 4q+2/3 are never read), so reads are broadcast-heavy
// (8 distinct 16B addresses for 64 lanes) and each lane does ONE
// ds_write_b16 instead of 4 replicated writes. No zero-init needed.
__device__ __forceinline__ void scan_body(
    char* smem, int bid, const bf16* __restrict__ xi,
    const int* __restrict__ dones, const float* __restrict__ bh_n,
    const bf16* __restrict__ whT, float* __restrict__ h_state,
    bf16* __restrict__ y, float* __restrict__ hidden_out, int chunk) {
  bf16 (*hb)[2][136]       = (bf16(*)[2][136])smem;               // 1088 B
  bf16 (*xibuf)[8][2][400] = (bf16(*)[8][2][400])(smem + 1088);   // 25600 B
  int  (*dn)[2]            = (int(*)[2])(smem + 26688);           // 2056 B

  __builtin_amdgcn_s_setprio(1);   // win SIMD arbitration vs worker waves

  int tid = threadIdx.x;
  int wave = tid >> 6, lane = tid & 63;
  int nl = lane & 15, q = lane >> 4;
  int b0 = bid * 2;
  int ch = q & 1;
  int hsel = q >> 1;
  int dim = wave * 16 + (hsel << 6) + nl;
  int hrow = nl & 1;

  for (int i = tid; i <= CT; i += 256) {
    int t = chunk * CT + i;
    dn[i][0] = (t < T_DIM) ? dones[t * B_DIM + b0] : 0;
    dn[i][1] = (t < T_DIM) ? dones[t * B_DIM + b0 + 1] : 0;
  }
  // per-thread staging slots (3 int4 per thread cover 8 steps x 2 chains x 384)
  int c0 = tid, c1 = 256 + tid, c2 = 512 + tid;
  int t0 = c0 / 96, p0 = c0 % 96, sc0 = p0 / 48, o0 = (p0 % 48) * 8;
  int t1 = c1 / 96, p1 = c1 % 96, sc1 = p1 / 48, o1 = (p1 % 48) * 8;
  int t2 = c2 / 96, p2 = c2 % 96, sc2 = p2 / 48, o2 = (p2 % 48) * 8;
  const long PSTR = (long)8 * B_DIM * G3;
  const bf16* pfs0 = xi + ((long)(8 + t0) * B_DIM + b0 + sc0) * G3 + o0;
  const bf16* pfs1 = xi + ((long)(8 + t1) * B_DIM + b0 + sc1) * G3 + o1;
  const bf16* pfs2 = xi + ((long)(8 + t2) * B_DIM + b0 + sc2) * G3 + o2;
  *(int4*)&xibuf[0][t0][sc0][o0] = *(const int4*)(xi + ((long)t0 * B_DIM + b0 + sc0) * G3 + o0);
  *(int4*)&xibuf[0][t1][sc1][o1] = *(const int4*)(xi + ((long)t1 * B_DIM + b0 + sc1) * G3 + o1);
  *(int4*)&xibuf[0][t2][sc2][o2] = *(const int4*)(xi + ((long)t2 * B_DIM + b0 + sc2) * G3 + o2);

  float hprev = h_state[(b0 + ch) * H_DIM + dim];
  hb[0][ch][dim] = (bf16)hprev;

  bf16x8 wf[6][4];
#pragma unroll
  for (int g = 0; g < 3; ++g)
#pragma unroll
    for (int hI = 0; hI < 2; ++hI)
#pragma unroll
      for (int kb = 0; kb < 4; ++kb)
        wf[g * 2 + hI][kb] =
            *(const bf16x8*)(whT + ((g * 8 + wave + 4 * hI) * 16 + nl) * H_DIM + kb * 32 + q * 8);
  float bhn = bh_n[dim];
  bf16* yp = y + (long)(b0 + ch) * H_DIM + dim;
  __syncthreads();

  int4 pfr0, pfr1, pfr2;

#define BAR()                                                                  \
  do {                                                                         \
    asm volatile("s_waitcnt lgkmcnt(0)" ::: "memory");                         \
    __builtin_amdgcn_sched_barrier(0);                                         \
    __builtin_amdgcn_s_barrier();                                              \
    __builtin_amdgcn_sched_barrier(0);                                         \
  } while (0)

#define MSTEP(HA, KB)                                                          \
  do {                                                                         \
    c0_ = MFMA(HA, wf[0][KB], c0_); c1_ = MFMA(HA, wf[1][KB], c1_);            \
    c2_ = MFMA(HA, wf[2][KB], c2_); c3_ = MFMA(HA, wf[3][KB], c3_);            \
    c4_ = MFMA(HA, wf[4][KB], c4_); c5_ = MFMA(HA, wf[5][KB], c5_);            \
  } while (0)

#define GSTEP(CUR, TS, TB, PF)                                                 \
  do {                                                                         \
    const int p_ = (TS) & 1;                                                   \
    bf16x8 ha0 = *(const bf16x8*)&hb[p_][hrow][0 * 32 + q * 8];                \
    bf16x8 ha1 = *(const bf16x8*)&hb[p_][hrow][1 * 32 + q * 8];                \
    bf16x8 ha2 = *(const bf16x8*)&hb[p_][hrow][2 * 32 + q * 8];                \
    bf16x8 ha3 = *(const bf16x8*)&hb[p_][hrow][3 * 32 + q * 8];                \
    const bf16* xrow_ = &xibuf[CUR][TS][ch][0];                                \
    unsigned urz_ = *(const unsigned*)(xrow_ + 2 * dim);                       \
    float xnv_ = (float)xrow_[256 + dim];                                      \
    int dnv_ = dn[(TB) + (TS) + 1][ch];                                        \
    if ((TS) == 0 && (PF)) {                                                   \
      pfr0 = *(const int4*)pfs0; pfs0 += PSTR;                                 \
      pfr1 = *(const int4*)pfs1; pfs1 += PSTR;                                 \
      pfr2 = *(const int4*)pfs2; pfs2 += PSTR;                                 \
    }                                                                          \
    f32x4 c0_ = {0.f, 0.f, 0.f, 0.f}, c1_ = {0.f, 0.f, 0.f, 0.f};             \
    f32x4 c2_ = {0.f, 0.f, 0.f, 0.f}, c3_ = {0.f, 0.f, 0.f, 0.f};             \
    f32x4 c4_ = {0.f, 0.f, 0.f, 0.f}, c5_ = {0.f, 0.f, 0.f, 0.f};             \
    MSTEP(ha0, 0); MSTEP(ha1, 1); MSTEP(ha2, 2); MSTEP(ha3, 3);                \
    if ((TS) == 7 && (PF)) {                                                   \
      *(int4*)&xibuf[(CUR) ^ 1][t0][sc0][o0] = pfr0;                           \
      *(int4*)&xibuf[(CUR) ^ 1][t1][sc1][o1] = pfr1;                           \
      *(int4*)&xibuf[(CUR) ^ 1][t2][sc2][o2] = pfr2;                           \
    }                                                                          \
    float hr_ = hsel ? (ch ? c1_[1] : c1_[0]) : (ch ? c0_[1] : c0_[0]);        \
    float hz_ = hsel ? (ch ? c3_[1] : c3_[0]) : (ch ? c2_[1] : c2_[0]);        \
    float hn_ = hsel ? (ch ? c5_[1] : c5_[0]) : (ch ? c4_[1] : c4_[0]);        \
    union { unsigned u; float f; } cvr_, cvz_;                                 \
    cvr_.u = urz_ << 16; cvz_.u = urz_ & 0xffff0000u;                          \
    float r_ = sigm(cvr_.f + hr_);                                             \
    float z_ = sigm(cvz_.f + hz_);                                             \
    float n_ = tanh_f(xnv_ + r_ * (hn_ + bhn));                                \
    float hnew_ = (1.0f - z_) * n_ + z_ * hprev;                               \
    float heff_ = dnv_ ? 0.0f : hnew_;                                         \
    *yp = (bf16)hnew_; yp += B_DIM * H_DIM;                                    \
    hb[p_ ^ 1][ch][dim] = (bf16)heff_;                                         \
    hprev = heff_;                                                             \
    BAR();                                                                     \
  } while (0)

  for (int tb = 0; tb < CT; tb += 16) {
    GSTEP(0, 0, tb, 1); GSTEP(0, 1, tb, 1); GSTEP(0, 2, tb, 1); GSTEP(0, 3, tb, 1);
    GSTEP(0, 4, tb, 1); GSTEP(0, 5, tb, 1); GSTEP(0, 6, tb, 1); GSTEP(0, 7, tb, 1);
    const int pfB = (tb + 16 < CT) ? 1 : 0;
    GSTEP(1, 0, tb + 8, pfB); GSTEP(1, 1, tb + 8, pfB); GSTEP(1, 2, tb + 8, pfB);
    GSTEP(1, 3, tb + 8, pfB); GSTEP(1, 4, tb + 8, pfB); GSTEP(1, 5, tb + 8, pfB);
    GSTEP(1, 6, tb + 8, pfB); GSTEP(1, 7, tb + 8, pfB);
  }
#undef GSTEP
#undef MSTEP
#undef BAR
  __builtin_amdgcn_s_setprio(0);

  // heff(last) == hnew(last) on the final chunk: dn[CT] there is 0 (t >= T_DIM)
  h_state[(b0 + ch) * H_DIM + dim] = hprev;
  if (chunk == NCHUNK - 1) hidden_out[(b0 + ch) * H_DIM + dim] = hprev;
}

// ---- heads body: weight-stationary, 512 rows (32 row-tiles) per block -------
__device__ __forceinline__ void heads_body(
    char* smem, int bid, const bf16* __restrict__ y,
    const float* __restrict__ ba1, const float* __restrict__ ba2,
    const float* __restrict__ bc1, const float* __restrict__ bc2,
    const bf16* __restrict__ wa1T, const bf16* __restrict__ wa2T,
    const bf16* __restrict__ wc1T, const bf16* __restrict__ wc2T,
    float* __restrict__ logits, float* __restrict__ v, int t_base) {
  bf16  (*y_lds)[136] = (bf16(*)[136])smem;              // 4352 B
  bf16  (*a1s)[136]   = (bf16(*)[136])(smem + 4352);     // 4352 B
  bf16  (*c1s)[136]   = (bf16(*)[136])(smem + 8704);     // 4352 B
  float (*s_o)[16]    = (float(*)[16])(smem + 13056);    // 1024 B
  float (*s_v)        = (float*)(smem + 14080);          // 64 B
  int tid = threadIdx.x, wave = tid >> 6, lane = tid & 63;
  int nl = lane & 15, q = lane >> 4;

  bf16x8 wa1f[2][4], wc1f[2][4], wa2f[4], wc2f[4];
  float ba1v[2], bc1v[2];
#pragma unroll
  for (int e = 0; e < 2; ++e) {
    int nt = wave * 2 + e;
#pragma unroll
    for (int kb = 0; kb < 4; ++kb) {
      wa1f[e][kb] = *(const bf16x8*)(wa1T + (nt * 16 + nl) * H_DIM + kb * 32 + q * 8);
      wc1f[e][kb] = *(const bf16x8*)(wc1T + (nt * 16 + nl) * H_DIM + kb * 32 + q * 8);
    }
    ba1v[e] = ba1[nt * 16 + nl];
    bc1v[e] = bc1[nt * 16 + nl];
  }
#pragma unroll
  for (int kb = 0; kb < 4; ++kb) {
    wa2f[kb] = *(const bf16x8*)(wa2T + nl * H_DIM + kb * 32 + q * 8);
    wc2f[kb] = *(const bf16x8*)(wc2T + nl * H_DIM + kb * 32 + q * 8);
  }
  float ba2v = ba2[nl], bc2v = bc2[0];

  int srow = tid >> 4, scol = (tid & 15) * 8;
  for (int rt = 0; rt < 32; ++rt) {
    int r0 = bid * 512 + rt * 16;          // chunk-local row base
    long gr0 = (long)t_base * B_DIM + r0;  // global row base
    *(int4*)&y_lds[srow][scol] = *(const int4*)(y + (long)(r0 + srow) * H_DIM + scol);
    __syncthreads();
    bf16x8 ya[4];
#pragma unroll
    for (int kb = 0; kb < 4; ++kb) ya[kb] = *(const bf16x8*)&y_lds[nl][kb * 32 + q * 8];
#pragma unroll
    for (int e = 0; e < 2; ++e) {
      f32x4 ca = {0.f, 0.f, 0.f, 0.f}, cc = {0.f, 0.f, 0.f, 0.f};
#pragma unroll
      for (int kb = 0; kb < 4; ++kb) {
        ca = MFMA(ya[kb], wa1f[e][kb], ca);
        cc = MFMA(ya[kb], wc1f[e][kb], cc);
      }
      int colb = (wave * 2 + e) * 16 + nl;
#pragma unroll
      for (int r = 0; r < 4; ++r) {
        float va = ca[r] + ba1v[e];
        float vc = cc[r] + bc1v[e];
        a1s[q * 4 + r][colb] = (bf16)(va > 0.f ? va : 0.f);
        c1s[q * 4 + r][colb] = (bf16)(vc > 0.f ? vc : 0.f);
      }
    }
    __syncthreads();
    if (wave == 0) {
      bf16x8 a1f[4];
#pragma unroll
      for (int kb = 0; kb < 4; ++kb) a1f[kb] = *(const bf16x8*)&a1s[nl][kb * 32 + q * 8];
      f32x4 c = {0.f, 0.f, 0.f, 0.f};
#pragma unroll
      for (int kb = 0; kb < 4; ++kb) c = MFMA(a1f[kb], wa2f[kb], c);
#pragma unroll
      for (int r = 0; r < 4; ++r) s_o[q * 4 + r][nl] = c[r] + ba2v;
    } else if (wave == 1) {
      bf16x8 c1f[4];
#pragma unroll
      for (int kb = 0; kb < 4; ++kb) c1f[kb] = *(const bf16x8*)&c1s[nl][kb * 32 + q * 8];
      f32x4 c = {0.f, 0.f, 0.f, 0.f};
#pragma unroll
      for (int kb = 0; kb < 4; ++kb) c = MFMA(c1f[kb], wc2f[kb], c);
      if (nl == 0) {
#pragma unroll
        for (int r = 0; r < 4; ++r) s_v[q * 4 + r] = c[r] + bc2v;
      }
    }
    __syncthreads();
    if (tid < 64) {
      *(int4*)(logits + gr0 * A_DIM + tid * 4) = *(const int4*)&s_o[tid >> 2][(tid & 3) * 4];
    } else if (tid < 80) {
      v[gr0 + (tid - 64)] = s_v[tid - 64];
    }
  }
}

// ---- fused pipeline kernel: scan(cs) ∥ phase1(cs+1) ∥ heads(cs-1) ------------
// 768 blocks = 3 blocks/CU (LDS-limited): 1 scan + 1 phase1 + 1 heads per CU.
__global__ __launch_bounds__(256, 3) void fused_k(
    const float* __restrict__ obs, const float* __restrict__ b_emb,
    const float* __restrict__ bi, const bf16* __restrict__ wembT,
    const bf16* __restrict__ wiT, bf16* __restrict__ xi0, bf16* __restrict__ xi1,
    const int* __restrict__ dones, const float* __restrict__ bh_n,
    const bf16* __restrict__ whT, float* __restrict__ h_state,
    bf16* __restrict__ y0, bf16* __restrict__ y1, float* __restrict__ hidden_out,
    const float* __restrict__ ba1, const float* __restrict__ ba2,
    const float* __restrict__ bc1, const float* __restrict__ bc2,
    const bf16* __restrict__ wa1T, const bf16* __restrict__ wa2T,
    const bf16* __restrict__ wc1T, const bf16* __restrict__ wc2T,
    float* __restrict__ logits, float* __restrict__ v, int cs) {
  __shared__ __align__(16) char smem[50176];
  int bid = blockIdx.x;
  if (bid < 256) {
    if (cs >= 0 && cs < NCHUNK)
      scan_body(smem, bid, (cs & 1) ? xi1 : xi0, dones, bh_n, whT, h_state,
                (cs & 1) ? y1 : y0, hidden_out, cs);
    return;
  }
  if (bid < 512) {
    int cp = cs + 1;
    if (cp >= 0 && cp < NCHUNK)
      phase1_body(smem, bid - 256, obs, b_emb, bi, wembT, wiT,
                  (cp & 1) ? xi1 : xi0, cp * CT * B_DIM);
    return;
  }
  {
    int ch2 = cs - 1;
    if (ch2 >= 0 && ch2 < NCHUNK)
      heads_body(smem, bid - 512, (ch2 & 1) ? y1 : y0, ba1, ba2, bc1, bc2,
                 wa1T, wa2T, wc1T, wc2T, logits, v, ch2 * CT);
  }
}

// ---------------- launch ------------------------------------------------------
extern "C" void kernel_launch(void* const* d_in, const int* in_sizes, int n_in,
                              void* d_out, int out_size, void* d_ws, size_t ws_size,
                              hipStream_t stream) {
  const float* hidden = (const float*)d_in[0];
  const float* obs    = (const float*)d_in[1];
  const int*   dones  = (const int*)d_in[2];
  const float* W_emb  = (const float*)d_in[3];
  const float* b_emb  = (const float*)d_in[4];
  const float* Wi     = (const float*)d_in[5];
  const float* bi     = (const float*)d_in[6];
  const float* Wh     = (const float*)d_in[7];
  const float* bh_n   = (const float*)d_in[8];
  const float* Wa1    = (const float*)d_in[9];
  const float* ba1    = (const float*)d_in[10];
  const float* Wa2    = (const float*)d_in[11];
  const float* ba2    = (const float*)d_in[12];
  const float* Wc1    = (const float*)d_in[13];
  const float* bc1    = (const float*)d_in[14];
  const float* Wc2    = (const float*)d_in[15];
  const float* bc2    = (const float*)d_in[16];

  float* out_hidden = (float*)d_out;
  float* out_logits = out_hidden + B_DIM * H_DIM;
  float* out_v      = out_logits + (long)T_DIM * B_DIM * A_DIM;

  char* ws = (char*)d_ws;
  bf16*  wembT   = (bf16*)(ws + 0);
  bf16*  wiT     = (bf16*)(ws + 16384);
  bf16*  whT     = (bf16*)(ws + 114688);
  bf16*  wa1T    = (bf16*)(ws + 212992);
  bf16*  wa2T    = (bf16*)(ws + 245760);
  bf16*  wc1T    = (bf16*)(ws + 249856);
  bf16*  wc2T    = (bf16*)(ws + 282624);
  float* h_state = (float*)(ws + 286720);
  bf16*  xi0     = (bf16*)(ws + 548864);       // 100.66 MB per chunk buffer
  bf16*  xi1     = (bf16*)(ws + 101212160);
  bf16*  y0      = (bf16*)(ws + 201875456);    // 33.55 MB per chunk buffer
  bf16*  y1      = (bf16*)(ws + 235429888);    // end 268.98 MB

  prep_k<<<816, 256, 0, stream>>>(hidden, dones, W_emb, Wi, Wh, Wa1, Wa2, Wc1, Wc2,
                                  wembT, wiT, whT, wa1T, wa2T, wc1T, wc2T, h_state);
  for (int cs = -1; cs <= NCHUNK; ++cs) {
    fused_k<<<768, 256, 0, stream>>>(obs, b_emb, bi, wembT, wiT, xi0, xi1,
                                     dones, bh_n, whT, h_state, y0, y1, out_hidden,
                                     ba1, ba2, bc1, bc2, wa1T, wa2T, wc1T, wc2T,
                                     out_logits, out_v, cs);
  }
  (void)in_sizes; (void)n_in; (void)out_size; (void)ws_size;
}

// Round 8
// 748.101 us; speedup vs baseline: 1.3393x; 1.2173x over previous
//
#include <hip/hip_runtime.h>

#define T_DIM 1024
#define B_DIM 512
#define OBS_DIM 64
#define H_DIM 128
#define G3 384
#define A_DIM 16
#define CT 256
#define NCHUNK 4

typedef __bf16 bf16;
typedef __attribute__((ext_vector_type(4))) __bf16 bf16x4;
typedef __attribute__((ext_vector_type(8))) __bf16 bf16x8;
typedef __attribute__((ext_vector_type(4))) float f32x4;

#define MFMA(a, b, c) __builtin_amdgcn_mfma_f32_16x16x32_bf16((a), (b), (c), 0, 0, 0)

__device__ __forceinline__ float sigm(float x) { return 1.0f / (1.0f + __expf(-x)); }
__device__ __forceinline__ float tanh_f(float x) { return 1.0f - 2.0f / (__expf(2.0f * x) + 1.0f); }

// ---------------- prep: bf16 transposed weights + h_state init ----------------
__global__ __launch_bounds__(256) void prep_k(
    const float* __restrict__ hidden, const int* __restrict__ dones,
    const float* __restrict__ W_emb, const float* __restrict__ Wi,
    const float* __restrict__ Wh, const float* __restrict__ Wa1,
    const float* __restrict__ Wa2, const float* __restrict__ Wc1,
    const float* __restrict__ Wc2,
    bf16* __restrict__ wembT, bf16* __restrict__ wiT, bf16* __restrict__ whT,
    bf16* __restrict__ wa1T, bf16* __restrict__ wa2T, bf16* __restrict__ wc1T,
    bf16* __restrict__ wc2T, float* __restrict__ h_state) {
  int i = blockIdx.x * 256 + threadIdx.x;
  if (i < 8192) { int n = i / OBS_DIM, k = i % OBS_DIM; wembT[i] = (bf16)W_emb[k * H_DIM + n]; return; }
  i -= 8192;
  if (i < 49152) { int g = i / H_DIM, k = i % H_DIM; wiT[i] = (bf16)Wi[k * G3 + g]; return; }
  i -= 49152;
  if (i < 49152) { int g = i / H_DIM, k = i % H_DIM; whT[i] = (bf16)Wh[k * G3 + g]; return; }
  i -= 49152;
  if (i < 16384) { int n = i / H_DIM, k = i % H_DIM; wa1T[i] = (bf16)Wa1[k * H_DIM + n]; return; }
  i -= 16384;
  if (i < 2048) { int a = i / H_DIM, k = i % H_DIM; wa2T[i] = (bf16)Wa2[k * A_DIM + a]; return; }
  i -= 2048;
  if (i < 16384) { int n = i / H_DIM, k = i % H_DIM; wc1T[i] = (bf16)Wc1[k * H_DIM + n]; return; }
  i -= 16384;
  if (i < 2048) { int r = i / H_DIM, k = i % H_DIM; wc2T[i] = (r == 0) ? (bf16)Wc2[k] : (bf16)0.0f; return; }
  i -= 2048;
  if (i < 65536) { int b = i / H_DIM; h_state[i] = dones[b] ? 0.0f : hidden[i]; return; }
}

// ================= role bodies (share one 50176-B LDS block) =================

// ---- phase1 body: weight-stationary, ntiles x 16 rows -----------------------
__device__ __forceinline__ void phase1_body(
    char* smem, int tile_base, int ntiles, const float* __restrict__ obs,
    const float* __restrict__ b_emb, const float* __restrict__ bi,
    const bf16* __restrict__ wembT, const bf16* __restrict__ wiT,
    bf16* __restrict__ xi, int row_base) {
  bf16 (*obs_lds)[72]  = (bf16(*)[72])smem;            // 2304 B
  bf16 (*emb_lds)[136] = (bf16(*)[136])(smem + 2304);  // 4352 B
  bf16 (*strip)[392]   = (bf16(*)[392])(smem + 6656);  // 12544 B
  int tid = threadIdx.x, wave = tid >> 6, lane = tid & 63;
  int nl = lane & 15, q = lane >> 4;

  bf16x8 we[2][2], wi_f[6][4];
  float bev[2], biv[6];
#pragma unroll
  for (int e = 0; e < 2; ++e) {
    int nt = wave * 2 + e;
#pragma unroll
    for (int kb = 0; kb < 2; ++kb)
      we[e][kb] = *(const bf16x8*)(wembT + (nt * 16 + nl) * OBS_DIM + kb * 32 + q * 8);
    bev[e] = b_emb[nt * 16 + nl];
  }
#pragma unroll
  for (int j = 0; j < 6; ++j) {
    int nt = wave * 6 + j;
#pragma unroll
    for (int kb = 0; kb < 4; ++kb)
      wi_f[j][kb] = *(const bf16x8*)(wiT + (nt * 16 + nl) * H_DIM + kb * 32 + q * 8);
    biv[j] = bi[nt * 16 + nl];
  }

  int srow = tid >> 4, scol = (tid & 15) * 4;
  for (int rt = 0; rt < ntiles; ++rt) {
    int r0 = (tile_base + rt) * 16;  // chunk-local row base
    {   // stage obs tile (f32 -> bf16), 256 thr x 1 float4
      const float* src = obs + ((long)row_base + r0 + srow) * OBS_DIM + scol;
      float4 vv = *(const float4*)src;
      bf16x4 b; b[0] = (bf16)vv.x; b[1] = (bf16)vv.y; b[2] = (bf16)vv.z; b[3] = (bf16)vv.w;
      *(bf16x4*)&obs_lds[srow][scol] = b;
    }
    __syncthreads();
    bf16x8 ao[2];
#pragma unroll
    for (int kb = 0; kb < 2; ++kb) ao[kb] = *(const bf16x8*)&obs_lds[nl][kb * 32 + q * 8];
#pragma unroll
    for (int e = 0; e < 2; ++e) {
      f32x4 c = {0.f, 0.f, 0.f, 0.f};
      c = MFMA(ao[0], we[e][0], c);
      c = MFMA(ao[1], we[e][1], c);
#pragma unroll
      for (int r = 0; r < 4; ++r) {
        float v = c[r] + bev[e];
        emb_lds[q * 4 + r][(wave * 2 + e) * 16 + nl] = (bf16)(v > 0.f ? v : 0.f);
      }
    }
    __syncthreads();
    bf16x8 ae[4];
#pragma unroll
    for (int kb = 0; kb < 4; ++kb) ae[kb] = *(const bf16x8*)&emb_lds[nl][kb * 32 + q * 8];
#pragma unroll
    for (int j = 0; j < 6; ++j) {
      int nt = wave * 6 + j;
      f32x4 c = {0.f, 0.f, 0.f, 0.f};
#pragma unroll
      for (int kb = 0; kb < 4; ++kb) c = MFMA(ae[kb], wi_f[j][kb], c);
      int gate = nt >> 3, dloc = (nt & 7) * 16 + nl;
      int pos = (gate < 2) ? (2 * dloc + gate) : (256 + dloc);
#pragma unroll
      for (int r = 0; r < 4; ++r) strip[q * 4 + r][pos] = (bf16)(c[r] + biv[j]);
    }
    __syncthreads();
    bf16* dst = xi + (long)r0 * G3;
#pragma unroll
    for (int it = 0; it < 3; ++it) {
      int e0 = (it * 256 + tid) * 8;
      int row = e0 / G3, col = e0 % G3;
      *(int4*)(dst + e0) = *(const int4*)&strip[row][col];
    }
    __syncthreads();
  }
}

// ---- scan body: GRU over CT steps, 2 chains per block (1 block/CU) ----------
// hb [2 dbuf][2 chains][136]: broadcast-heavy reads, 1 ds_write_b16 per lane.
__device__ __forceinline__ void scan_body(
    char* smem, int bid, const bf16* __restrict__ xi,
    const int* __restrict__ dones, const float* __restrict__ bh_n,
    const bf16* __restrict__ whT, float* __restrict__ h_state,
    bf16* __restrict__ y, float* __restrict__ hidden_out, int chunk) {
  bf16 (*hb)[2][136]       = (bf16(*)[2][136])smem;               // 1088 B
  bf16 (*xibuf)[8][2][400] = (bf16(*)[8][2][400])(smem + 1088);   // 25600 B
  int  (*dn)[2]            = (int(*)[2])(smem + 26688);           // 2056 B

  __builtin_amdgcn_s_setprio(1);   // win SIMD arbitration vs worker waves

  int tid = threadIdx.x;
  int wave = tid >> 6, lane = tid & 63;
  int nl = lane & 15, q = lane >> 4;
  int b0 = bid * 2;
  int ch = q & 1;
  int hsel = q >> 1;
  int dim = wave * 16 + (hsel << 6) + nl;
  int hrow = nl & 1;

  for (int i = tid; i <= CT; i += 256) {
    int t = chunk * CT + i;
    dn[i][0] = (t < T_DIM) ? dones[t * B_DIM + b0] : 0;
    dn[i][1] = (t < T_DIM) ? dones[t * B_DIM + b0 + 1] : 0;
  }
  // per-thread staging slots (3 int4 per thread cover 8 steps x 2 chains x 384)
  int c0 = tid, c1 = 256 + tid, c2 = 512 + tid;
  int t0 = c0 / 96, p0 = c0 % 96, sc0 = p0 / 48, o0 = (p0 % 48) * 8;
  int t1 = c1 / 96, p1 = c1 % 96, sc1 = p1 / 48, o1 = (p1 % 48) * 8;
  int t2 = c2 / 96, p2 = c2 % 96, sc2 = p2 / 48, o2 = (p2 % 48) * 8;
  const long PSTR = (long)8 * B_DIM * G3;
  const bf16* pfs0 = xi + ((long)(8 + t0) * B_DIM + b0 + sc0) * G3 + o0;
  const bf16* pfs1 = xi + ((long)(8 + t1) * B_DIM + b0 + sc1) * G3 + o1;
  const bf16* pfs2 = xi + ((long)(8 + t2) * B_DIM + b0 + sc2) * G3 + o2;
  *(int4*)&xibuf[0][t0][sc0][o0] = *(const int4*)(xi + ((long)t0 * B_DIM + b0 + sc0) * G3 + o0);
  *(int4*)&xibuf[0][t1][sc1][o1] = *(const int4*)(xi + ((long)t1 * B_DIM + b0 + sc1) * G3 + o1);
  *(int4*)&xibuf[0][t2][sc2][o2] = *(const int4*)(xi + ((long)t2 * B_DIM + b0 + sc2) * G3 + o2);

  float hprev = h_state[(b0 + ch) * H_DIM + dim];
  hb[0][ch][dim] = (bf16)hprev;

  bf16x8 wf[6][4];
#pragma unroll
  for (int g = 0; g < 3; ++g)
#pragma unroll
    for (int hI = 0; hI < 2; ++hI)
#pragma unroll
      for (int kb = 0; kb < 4; ++kb)
        wf[g * 2 + hI][kb] =
            *(const bf16x8*)(whT + ((g * 8 + wave + 4 * hI) * 16 + nl) * H_DIM + kb * 32 + q * 8);
  float bhn = bh_n[dim];
  bf16* yp = y + (long)(b0 + ch) * H_DIM + dim;
  __syncthreads();

  int4 pfr0, pfr1, pfr2;

#define BAR()                                                                  \
  do {                                                                         \
    asm volatile("s_waitcnt lgkmcnt(0)" ::: "memory");                         \
    __builtin_amdgcn_sched_barrier(0);                                         \
    __builtin_amdgcn_s_barrier();                                              \
    __builtin_amdgcn_sched_barrier(0);                                         \
  } while (0)

#define MSTEP(HA, KB)                                                          \
  do {                                                                         \
    c0_ = MFMA(HA, wf[0][KB], c0_); c1_ = MFMA(HA, wf[1][KB], c1_);            \
    c2_ = MFMA(HA, wf[2][KB], c2_); c3_ = MFMA(HA, wf[3][KB], c3_);            \
    c4_ = MFMA(HA, wf[4][KB], c4_); c5_ = MFMA(HA, wf[5][KB], c5_);            \
  } while (0)

#define GSTEP(CUR, TS, TB, PF)                                                 \
  do {                                                                         \
    const int p_ = (TS) & 1;                                                   \
    bf16x8 ha0 = *(const bf16x8*)&hb[p_][hrow][0 * 32 + q * 8];                \
    bf16x8 ha1 = *(const bf16x8*)&hb[p_][hrow][1 * 32 + q * 8];                \
    bf16x8 ha2 = *(const bf16x8*)&hb[p_][hrow][2 * 32 + q * 8];                \
    bf16x8 ha3 = *(const bf16x8*)&hb[p_][hrow][3 * 32 + q * 8];                \
    const bf16* xrow_ = &xibuf[CUR][TS][ch][0];                                \
    unsigned urz_ = *(const unsigned*)(xrow_ + 2 * dim);                       \
    float xnv_ = (float)xrow_[256 + dim];                                      \
    int dnv_ = dn[(TB) + (TS) + 1][ch];                                        \
    if ((TS) == 0 && (PF)) {                                                   \
      pfr0 = *(const int4*)pfs0; pfs0 += PSTR;                                 \
      pfr1 = *(const int4*)pfs1; pfs1 += PSTR;                                 \
      pfr2 = *(const int4*)pfs2; pfs2 += PSTR;                                 \
    }                                                                          \
    f32x4 c0_ = {0.f, 0.f, 0.f, 0.f}, c1_ = {0.f, 0.f, 0.f, 0.f};             \
    f32x4 c2_ = {0.f, 0.f, 0.f, 0.f}, c3_ = {0.f, 0.f, 0.f, 0.f};             \
    f32x4 c4_ = {0.f, 0.f, 0.f, 0.f}, c5_ = {0.f, 0.f, 0.f, 0.f};             \
    MSTEP(ha0, 0); MSTEP(ha1, 1); MSTEP(ha2, 2); MSTEP(ha3, 3);                \
    if ((TS) == 7 && (PF)) {                                                   \
      *(int4*)&xibuf[(CUR) ^ 1][t0][sc0][o0] = pfr0;                           \
      *(int4*)&xibuf[(CUR) ^ 1][t1][sc1][o1] = pfr1;                           \
      *(int4*)&xibuf[(CUR) ^ 1][t2][sc2][o2] = pfr2;                           \
    }                                                                          \
    float hr_ = hsel ? (ch ? c1_[1] : c1_[0]) : (ch ? c0_[1] : c0_[0]);        \
    float hz_ = hsel ? (ch ? c3_[1] : c3_[0]) : (ch ? c2_[1] : c2_[0]);        \
    float hn_ = hsel ? (ch ? c5_[1] : c5_[0]) : (ch ? c4_[1] : c4_[0]);        \
    union { unsigned u; float f; } cvr_, cvz_;                                 \
    cvr_.u = urz_ << 16; cvz_.u = urz_ & 0xffff0000u;                          \
    float r_ = sigm(cvr_.f + hr_);                                             \
    float z_ = sigm(cvz_.f + hz_);                                             \
    float n_ = tanh_f(xnv_ + r_ * (hn_ + bhn));                                \
    float hnew_ = (1.0f - z_) * n_ + z_ * hprev;                               \
    float heff_ = dnv_ ? 0.0f : hnew_;                                         \
    *yp = (bf16)hnew_; yp += B_DIM * H_DIM;                                    \
    hb[p_ ^ 1][ch][dim] = (bf16)heff_;                                         \
    hprev = heff_;                                                             \
    BAR();                                                                     \
  } while (0)

  for (int tb = 0; tb < CT; tb += 16) {
    GSTEP(0, 0, tb, 1); GSTEP(0, 1, tb, 1); GSTEP(0, 2, tb, 1); GSTEP(0, 3, tb, 1);
    GSTEP(0, 4, tb, 1); GSTEP(0, 5, tb, 1); GSTEP(0, 6, tb, 1); GSTEP(0, 7, tb, 1);
    const int pfB = (tb + 16 < CT) ? 1 : 0;
    GSTEP(1, 0, tb + 8, pfB); GSTEP(1, 1, tb + 8, pfB); GSTEP(1, 2, tb + 8, pfB);
    GSTEP(1, 3, tb + 8, pfB); GSTEP(1, 4, tb + 8, pfB); GSTEP(1, 5, tb + 8, pfB);
    GSTEP(1, 6, tb + 8, pfB); GSTEP(1, 7, tb + 8, pfB);
  }
#undef GSTEP
#undef MSTEP
#undef BAR
  __builtin_amdgcn_s_setprio(0);

  // heff(last) == hnew(last) on the final chunk: dn[CT] there is 0 (t >= T_DIM)
  h_state[(b0 + ch) * H_DIM + dim] = hprev;
  if (chunk == NCHUNK - 1) hidden_out[(b0 + ch) * H_DIM + dim] = hprev;
}

// ---- heads body: weight-stationary, ntiles x 16 rows ------------------------
__device__ __forceinline__ void heads_body(
    char* smem, int tile_base, int ntiles, const bf16* __restrict__ y,
    const float* __restrict__ ba1, const float* __restrict__ ba2,
    const float* __restrict__ bc1, const float* __restrict__ bc2,
    const bf16* __restrict__ wa1T, const bf16* __restrict__ wa2T,
    const bf16* __restrict__ wc1T, const bf16* __restrict__ wc2T,
    float* __restrict__ logits, float* __restrict__ v, int t_base) {
  bf16  (*y_lds)[136] = (bf16(*)[136])smem;              // 4352 B
  bf16  (*a1s)[136]   = (bf16(*)[136])(smem + 4352);     // 4352 B
  bf16  (*c1s)[136]   = (bf16(*)[136])(smem + 8704);     // 4352 B
  float (*s_o)[16]    = (float(*)[16])(smem + 13056);    // 1024 B
  float (*s_v)        = (float*)(smem + 14080);          // 64 B
  int tid = threadIdx.x, wave = tid >> 6, lane = tid & 63;
  int nl = lane & 15, q = lane >> 4;

  bf16x8 wa1f[2][4], wc1f[2][4], wa2f[4], wc2f[4];
  float ba1v[2], bc1v[2];
#pragma unroll
  for (int e = 0; e < 2; ++e) {
    int nt = wave * 2 + e;
#pragma unroll
    for (int kb = 0; kb < 4; ++kb) {
      wa1f[e][kb] = *(const bf16x8*)(wa1T + (nt * 16 + nl) * H_DIM + kb * 32 + q * 8);
      wc1f[e][kb] = *(const bf16x8*)(wc1T + (nt * 16 + nl) * H_DIM + kb * 32 + q * 8);
    }
    ba1v[e] = ba1[nt * 16 + nl];
    bc1v[e] = bc1[nt * 16 + nl];
  }
#pragma unroll
  for (int kb = 0; kb < 4; ++kb) {
    wa2f[kb] = *(const bf16x8*)(wa2T + nl * H_DIM + kb * 32 + q * 8);
    wc2f[kb] = *(const bf16x8*)(wc2T + nl * H_DIM + kb * 32 + q * 8);
  }
  float ba2v = ba2[nl], bc2v = bc2[0];

  int srow = tid >> 4, scol = (tid & 15) * 8;
  for (int rt = 0; rt < ntiles; ++rt) {
    int r0 = (tile_base + rt) * 16;        // chunk-local row base
    long gr0 = (long)t_base * B_DIM + r0;  // global row base
    *(int4*)&y_lds[srow][scol] = *(const int4*)(y + (long)(r0 + srow) * H_DIM + scol);
    __syncthreads();
    bf16x8 ya[4];
#pragma unroll
    for (int kb = 0; kb < 4; ++kb) ya[kb] = *(const bf16x8*)&y_lds[nl][kb * 32 + q * 8];
#pragma unroll
    for (int e = 0; e < 2; ++e) {
      f32x4 ca = {0.f, 0.f, 0.f, 0.f}, cc = {0.f, 0.f, 0.f, 0.f};
#pragma unroll
      for (int kb = 0; kb < 4; ++kb) {
        ca = MFMA(ya[kb], wa1f[e][kb], ca);
        cc = MFMA(ya[kb], wc1f[e][kb], cc);
      }
      int colb = (wave * 2 + e) * 16 + nl;
#pragma unroll
      for (int r = 0; r < 4; ++r) {
        float va = ca[r] + ba1v[e];
        float vc = cc[r] + bc1v[e];
        a1s[q * 4 + r][colb] = (bf16)(va > 0.f ? va : 0.f);
        c1s[q * 4 + r][colb] = (bf16)(vc > 0.f ? vc : 0.f);
      }
    }
    __syncthreads();
    if (wave == 0) {
      bf16x8 a1f[4];
#pragma unroll
      for (int kb = 0; kb < 4; ++kb) a1f[kb] = *(const bf16x8*)&a1s[nl][kb * 32 + q * 8];
      f32x4 c = {0.f, 0.f, 0.f, 0.f};
#pragma unroll
      for (int kb = 0; kb < 4; ++kb) c = MFMA(a1f[kb], wa2f[kb], c);
#pragma unroll
      for (int r = 0; r < 4; ++r) s_o[q * 4 + r][nl] = c[r] + ba2v;
    } else if (wave == 1) {
      bf16x8 c1f[4];
#pragma unroll
      for (int kb = 0; kb < 4; ++kb) c1f[kb] = *(const bf16x8*)&c1s[nl][kb * 32 + q * 8];
      f32x4 c = {0.f, 0.f, 0.f, 0.f};
#pragma unroll
      for (int kb = 0; kb < 4; ++kb) c = MFMA(c1f[kb], wc2f[kb], c);
      if (nl == 0) {
#pragma unroll
        for (int r = 0; r < 4; ++r) s_v[q * 4 + r] = c[r] + bc2v;
      }
    }
    __syncthreads();
    if (tid < 64) {
      *(int4*)(logits + gr0 * A_DIM + tid * 4) = *(const int4*)&s_o[tid >> 2][(tid & 3) * 4];
    } else if (tid < 80) {
      v[gr0 + (tid - 64)] = s_v[tid - 64];
    }
    __syncthreads();
  }
}

// ---- fused pipeline: scan(cs) ∥ merged-worker{phase1(cs+1); heads(cs-1)} -----
// 512 blocks = 2/CU: 1 scan + 1 worker per CU (fewer resident waves contending
// with the prio-1 scan wave than the previous 3/CU split). Edge launches
// (cs==-1 / cs==NCHUNK) spread the single remaining role over ALL 512 blocks.
__global__ __launch_bounds__(256, 2) void fused_k(
    const float* __restrict__ obs, const float* __restrict__ b_emb,
    const float* __restrict__ bi, const bf16* __restrict__ wembT,
    const bf16* __restrict__ wiT, bf16* __restrict__ xi0, bf16* __restrict__ xi1,
    const int* __restrict__ dones, const float* __restrict__ bh_n,
    const bf16* __restrict__ whT, float* __restrict__ h_state,
    bf16* __restrict__ y0, bf16* __restrict__ y1, float* __restrict__ hidden_out,
    const float* __restrict__ ba1, const float* __restrict__ ba2,
    const float* __restrict__ bc1, const float* __restrict__ bc2,
    const bf16* __restrict__ wa1T, const bf16* __restrict__ wa2T,
    const bf16* __restrict__ wc1T, const bf16* __restrict__ wc2T,
    float* __restrict__ logits, float* __restrict__ v, int cs) {
  __shared__ __align__(16) char smem[50176];
  int bid = blockIdx.x;
  if (cs == -1) {  // wide edge: phase1(0) over all 512 blocks
    phase1_body(smem, bid * 16, 16, obs, b_emb, bi, wembT, wiT, xi0, 0);
    return;
  }
  if (cs == NCHUNK) {  // wide edge: heads(NCHUNK-1) over all 512 blocks
    heads_body(smem, bid * 16, 16, ((NCHUNK - 1) & 1) ? y1 : y0, ba1, ba2, bc1,
               bc2, wa1T, wa2T, wc1T, wc2T, logits, v, (NCHUNK - 1) * CT);
    return;
  }
  if (bid < 256) {
    scan_body(smem, bid, (cs & 1) ? xi1 : xi0, dones, bh_n, whT, h_state,
              (cs & 1) ? y1 : y0, hidden_out, cs);
    return;
  }
  {  // merged worker
    int wb = bid - 256;
    int cp = cs + 1;
    if (cp < NCHUNK)
      phase1_body(smem, wb * 32, 32, obs, b_emb, bi, wembT, wiT,
                  (cp & 1) ? xi1 : xi0, cp * CT * B_DIM);
    int ch2 = cs - 1;
    if (ch2 >= 0)
      heads_body(smem, wb * 32, 32, (ch2 & 1) ? y1 : y0, ba1, ba2, bc1, bc2,
                 wa1T, wa2T, wc1T, wc2T, logits, v, ch2 * CT);
  }
}

// ---------------- launch ------------------------------------------------------
extern "C" void kernel_launch(void* const* d_in, const int* in_sizes, int n_in,
                              void* d_out, int out_size, void* d_ws, size_t ws_size,
                              hipStream_t stream) {
  const float* hidden = (const float*)d_in[0];
  const float* obs    = (const float*)d_in[1];
  const int*   dones  = (const int*)d_in[2];
  const float* W_emb  = (const float*)d_in[3];
  const float* b_emb  = (const float*)d_in[4];
  const float* Wi     = (const float*)d_in[5];
  const float* bi     = (const float*)d_in[6];
  const float* Wh     = (const float*)d_in[7];
  const float* bh_n   = (const float*)d_in[8];
  const float* Wa1    = (const float*)d_in[9];
  const float* ba1    = (const float*)d_in[10];
  const float* Wa2    = (const float*)d_in[11];
  const float* ba2    = (const float*)d_in[12];
  const float* Wc1    = (const float*)d_in[13];
  const float* bc1    = (const float*)d_in[14];
  const float* Wc2    = (const float*)d_in[15];
  const float* bc2    = (const float*)d_in[16];

  float* out_hidden = (float*)d_out;
  float* out_logits = out_hidden + B_DIM * H_DIM;
  float* out_v      = out_logits + (long)T_DIM * B_DIM * A_DIM;

  char* ws = (char*)d_ws;
  bf16*  wembT   = (bf16*)(ws + 0);
  bf16*  wiT     = (bf16*)(ws + 16384);
  bf16*  whT     = (bf16*)(ws + 114688);
  bf16*  wa1T    = (bf16*)(ws + 212992);
  bf16*  wa2T    = (bf16*)(ws + 245760);
  bf16*  wc1T    = (bf16*)(ws + 249856);
  bf16*  wc2T    = (bf16*)(ws + 282624);
  float* h_state = (float*)(ws + 286720);
  bf16*  xi0     = (bf16*)(ws + 548864);       // 100.66 MB per chunk buffer
  bf16*  xi1     = (bf16*)(ws + 101212160);
  bf16*  y0      = (bf16*)(ws + 201875456);    // 33.55 MB per chunk buffer
  bf16*  y1      = (bf16*)(ws + 235429888);    // end 268.98 MB

  prep_k<<<816, 256, 0, stream>>>(hidden, dones, W_emb, Wi, Wh, Wa1, Wa2, Wc1, Wc2,
                                  wembT, wiT, whT, wa1T, wa2T, wc1T, wc2T, h_state);
  for (int cs = -1; cs <= NCHUNK; ++cs) {
    fused_k<<<512, 256, 0, stream>>>(obs, b_emb, bi, wembT, wiT, xi0, xi1,
                                     dones, bh_n, whT, h_state, y0, y1, out_hidden,
                                     ba1, ba2, bc1, bc2, wa1T, wa2T, wc1T, wc2T,
                                     out_logits, out_v, cs);
  }
  (void)in_sizes; (void)n_in; (void)out_size; (void)ws_size;
}